// Round 12
// baseline (280.323 us; speedup 1.0000x reference)
//
#include <hip/hip_runtime.h>
#include <stdint.h>
#include <math.h>

// MultiGeometryAttention — f32 in/out. B=2 T=2048 C=1024 H=16 HD=64.
// heads 0-5 sdpa(0.125) | 6-9 hyperbolic(curvature) | 10-15 cos-normalized sdpa(8).
// History: R13 316. R16 287 (attn reg-batch loads -> 88us). R20 285 (swapped
// QK^T, in-reg P, LDS->0). R21 278 (B hi-only GEMM + XCD swizzle). R22 FAILED
// (no-split-K: serial chain). R23 266.9 (gemm0 V-third lo-skip). R24 264.0 =
// BEST (K/V reg time-share; occupancy test NULL -> attn chain-bound, PARKED:
// 5 experiments all null/neg; 88us floor at ~1 wave/SIMD, ~6600 cyc/ktile).
// R25: (a) split-K chunk 8->16: 3072 wave-tasks in 3 uniform rounds of 1024
// (round1 all size-16; rounds 2/3 sizes 16..1 descending) — balance by
// construction; PART 41.6W+43R -> 26+26 MB; 2048 fewer prologues.
// (b) fuse 3 split kernels into one launch; BPW1 relocated to ws[83886080)
// (free in BOTH phases) so proj_w split runs up front. Predict total ~252.
// WS (proven peak 94,896,128 B):
//  phase1: AX[0,16777216) BW1[16777216,23068672) | QKVF[33554432,83886080)
//          BPW1[83886080,85983232)
//  post-prep: Q2[0,16777216) K2hi[16777216,25165824) V2[25165824,33554432)
//             PART[33554432,59506688) BPW1[83886080,85983232)
//  post-attn: AY[0,16777216) | QQ[94371840) KK[94633984)

typedef __bf16 bf16x8 __attribute__((ext_vector_type(8)));
typedef float f32x4 __attribute__((ext_vector_type(4)));

static __device__ __forceinline__ float bf2f(unsigned short u) {
  union { unsigned int i; float f; } v; v.i = ((unsigned int)u) << 16; return v.f;
}
static __device__ __forceinline__ unsigned short f2bf(float f) {
  union { float f; unsigned int i; } v; v.f = f;
  unsigned int x = v.i;
  x += 0x7fffu + ((x >> 16) & 1u);   // RNE
  return (unsigned short)(x >> 16);
}

// direct global->LDS async copy, 16B/lane (gemm staging only).
static __device__ __forceinline__ void async_copy16(const void* gsrc, void* ldst) {
  auto* lp = reinterpret_cast<__attribute__((address_space(3))) unsigned int*>(
      reinterpret_cast<uintptr_t>(ldst));
  auto* gp = reinterpret_cast<const __attribute__((address_space(1))) unsigned int*>(
      reinterpret_cast<uintptr_t>(gsrc));
  __builtin_amdgcn_global_load_lds(gp, lp, 16, 0, 0);
}

// Fused input splitting (one launch):
//  blocks [0,4096):       x      -> AX   [hi|lo] 2048-wide
//  blocks [4096,7168):    qkv_w  -> BW1  hi-only 1024-wide
//  blocks [7168,8192):    proj_w -> BPW1 hi-only 1024-wide
__global__ __launch_bounds__(256) void split_all(
    const float* __restrict__ x, const float* __restrict__ qkv_w,
    const float* __restrict__ proj_w, unsigned short* __restrict__ AX,
    unsigned short* __restrict__ BW1, unsigned short* __restrict__ BPW1) {
  const int bid = blockIdx.x;
  const int kq = threadIdx.x * 4;
  if (bid < 4096) {
    const int row = bid;
    const f32x4 v = *(const f32x4*)(x + (size_t)row * 1024 + kq);
    unsigned short hi[4], lo[4];
#pragma unroll
    for (int i = 0; i < 4; ++i) {
      hi[i] = f2bf(v[i]);
      lo[i] = f2bf(v[i] - bf2f(hi[i]));   // exact residual in f32
    }
    uint2 uh, ul;
    uh.x = (unsigned)hi[0] | ((unsigned)hi[1] << 16);
    uh.y = (unsigned)hi[2] | ((unsigned)hi[3] << 16);
    ul.x = (unsigned)lo[0] | ((unsigned)lo[1] << 16);
    ul.y = (unsigned)lo[2] | ((unsigned)lo[3] << 16);
    unsigned short* op = AX + (size_t)row * 2048 + kq;
    *(uint2*)(op)        = uh;
    *(uint2*)(op + 1024) = ul;
  } else {
    const bool isq = (bid < 7168);
    const int row = isq ? (bid - 4096) : (bid - 7168);
    const float* src = isq ? qkv_w : proj_w;
    unsigned short* dst = isq ? BW1 : BPW1;
    const f32x4 v = *(const f32x4*)(src + (size_t)row * 1024 + kq);
    uint2 uh;
    uh.x = (unsigned)f2bf(v[0]) | ((unsigned)f2bf(v[1]) << 16);
    uh.y = (unsigned)f2bf(v[2]) | ((unsigned)f2bf(v[3]) << 16);
    *(uint2*)(dst + (size_t)row * 1024 + kq) = uh;
  }
}

// C[m][n] = sum_k (Ahi[m][k]+Alo[m][k])*B[n][k] (+bias[n]) -> f32.
// A: [M][2*Kr] hi|lo. B: [N][Kr] hi-only. 128x128 tile, BK=64 real-k, 4 waves,
// two MFMAs per frag pair. XOR-swizzled LDS. Bijective XCD swizzle (nwg%8==0).
// Tiles with n0 >= loN skip the lo product entirely (V-third of gemm0: output
// is bf16-truncated downstream, lo contribution below truncation error).
template <int HASBIAS>
__global__ __launch_bounds__(256) void gemm_bt2(
    const unsigned short* __restrict__ A, const unsigned short* __restrict__ Bm,
    float* __restrict__ C, const float* __restrict__ bias,
    int NX, int N_, int Kr, int loN) {
  alignas(16) __shared__ unsigned short smAh[128 * 64];
  alignas(16) __shared__ unsigned short smAl[128 * 64];
  alignas(16) __shared__ unsigned short smB [128 * 64];
  const int tid = threadIdx.x;
  const int lane = tid & 63;
  const int wvi = tid >> 6;
  const int wm = wvi >> 1, wn = wvi & 1;
  const int cpx = gridDim.x >> 3;
  const int wgid = ((int)blockIdx.x & 7) * cpx + ((int)blockIdx.x >> 3);
  const long m0 = (long)(wgid / NX) * 128, n0 = (long)(wgid % NX) * 128;
  const int K2w = Kr * 2;
  const bool skiplo = (n0 >= (long)loN);   // wave-uniform

  const f32x4 zero4 = {0.f, 0.f, 0.f, 0.f};
  f32x4 acc[4][4];
#pragma unroll
  for (int i = 0; i < 4; ++i)
#pragma unroll
    for (int j = 0; j < 4; ++j) acc[i][j] = zero4;

  int mrow[4], gg[4];
#pragma unroll
  for (int w = 0; w < 4; ++w) {
    int c = w * 256 + tid;
    mrow[w] = c >> 3;
    gg[w] = (c & 7) ^ ((c >> 3) & 7);
  }

  const int kTiles = Kr >> 6;
  for (int kt = 0; kt < kTiles; ++kt) {
    if (kt) __syncthreads();
    const int kb = kt << 6;
#pragma unroll
    for (int w = 0; w < 4; ++w) {
      const int c = w * 256 + tid;
      const size_t arow = (size_t)(m0 + mrow[w]) * K2w + kb + gg[w] * 8;
      async_copy16(A + arow,        (char*)smAh + c * 16);
      if (!skiplo)
        async_copy16(A + arow + Kr, (char*)smAl + c * 16);
      async_copy16(Bm + (size_t)(n0 + mrow[w]) * Kr + kb + gg[w] * 8,
                   (char*)smB + c * 16);
    }
    __syncthreads();
#pragma unroll
    for (int ks = 0; ks < 2; ++ks) {
      bf16x8 afh[4], afl[4], bg[4];
#pragma unroll
      for (int i = 0; i < 4; ++i) {
        const int ra = wm * 64 + i * 16 + (lane & 15);
        const int ga = (ks * 4 + (lane >> 4)) ^ (ra & 7);
        afh[i] = *(const bf16x8*)((const char*)smAh + ra * 128 + ga * 16);
        if (!skiplo)
          afl[i] = *(const bf16x8*)((const char*)smAl + ra * 128 + ga * 16);
        const int rb = wn * 64 + i * 16 + (lane & 15);
        const int gb2 = (ks * 4 + (lane >> 4)) ^ (rb & 7);
        bg[i] = *(const bf16x8*)((const char*)smB + rb * 128 + gb2 * 16);
      }
#pragma unroll
      for (int i = 0; i < 4; ++i)
#pragma unroll
        for (int j = 0; j < 4; ++j) {
          acc[i][j] = __builtin_amdgcn_mfma_f32_16x16x32_bf16(afh[i], bg[j], acc[i][j], 0, 0, 0);
          if (!skiplo)
            acc[i][j] = __builtin_amdgcn_mfma_f32_16x16x32_bf16(afl[i], bg[j], acc[i][j], 0, 0, 0);
        }
    }
  }

  const int r0 = wm * 64 + (lane >> 4) * 4;
  const int c0 = wn * 64 + (lane & 15);
#pragma unroll
  for (int j = 0; j < 4; ++j) {
    const long col = n0 + c0 + j * 16;
    float bv = 0.f;
    if (HASBIAS) bv = bias[col];
#pragma unroll
    for (int i = 0; i < 4; ++i) {
#pragma unroll
      for (int r = 0; r < 4; ++r) {
        const long row = m0 + r0 + i * 16 + r;
        C[row * N_ + col] = acc[i][j][r] + bv;
      }
    }
  }
}

// prep: rotary q,k; norms; normalize h>=10; fold sscale*log2e into q (geom0/2);
// emit fragment-linear tiles. Q2: [hi|lo] 8 frags/qw. K2: hi-only 8 frags/ktile.
// V2: 8 frags/ktile.
__global__ __launch_bounds__(256) void prep(
    const float* __restrict__ qkvf, unsigned short* __restrict__ Q2,
    unsigned short* __restrict__ K2, unsigned short* __restrict__ V2,
    float* __restrict__ qq, float* __restrict__ kk, const float* __restrict__ curvg) {
  __shared__ unsigned short Vl[64 * 66];
  const int tid = threadIdx.x;
  const int zz = blockIdx.x;
  const int ttile = zz & 31, bh = zz >> 5;
  const int b = bh >> 4, h = bh & 15;
  const int t0 = ttile * 64;
  const int tr = tid >> 2, seg = tid & 3;
  const int t = t0 + tr;
  const float* src = qkvf + ((size_t)(b * 2048 + t)) * 3072 + h * 64 + seg * 16;

  float qv[16], kv[16], vv[16];
#pragma unroll
  for (int c = 0; c < 4; ++c) {
    const f32x4 a  = *(const f32x4*)(src + c * 4);
    const f32x4 bb = *(const f32x4*)(src + 1024 + c * 4);
    const f32x4 cc = *(const f32x4*)(src + 2048 + c * 4);
#pragma unroll
    for (int e = 0; e < 4; ++e) { qv[c*4+e] = a[e]; kv[c*4+e] = bb[e]; vv[c*4+e] = cc[e]; }
  }
  float qr[16], kr[16];
#pragma unroll
  for (int e = 0; e < 16; ++e) {
    const int d = seg * 16 + e;
    const int i = d & 31;
    const float invf = exp2f(-0.41524101186109286f * (float)i);  // 10000^(-i/32)
    float sn, cs;
    sincosf((float)t * invf, &sn, &cs);
    const float qo = __shfl_xor(qv[e], 2, 64);
    const float ko = __shfl_xor(kv[e], 2, 64);
    qr[e] = (d < 32) ? (qv[e] * cs + qo * sn) : (qv[e] * cs - qo * sn);
    kr[e] = (d < 32) ? (kv[e] * cs + ko * sn) : (kv[e] * cs - ko * sn);
  }
  float sq = 0.f, sk = 0.f;
#pragma unroll
  for (int e = 0; e < 16; ++e) { sq += qr[e] * qr[e]; sk += kr[e] * kr[e]; }
  sq += __shfl_xor(sq, 1, 64); sq += __shfl_xor(sq, 2, 64);
  sk += __shfl_xor(sk, 1, 64); sk += __shfl_xor(sk, 2, 64);
  float qscale = 0.125f * 1.4426950408889634f;   // geom0: fold sscale*log2e
  if (h >= 10) {
    const float rq = 1.0f / fmaxf(sqrtf(sq), 1e-12f);
    const float rk = 1.0f / fmaxf(sqrtf(sk), 1e-12f);
#pragma unroll
    for (int e = 0; e < 16; ++e) { qr[e] *= rq; kr[e] *= rk; }
    qscale = 8.0f * 1.4426950408889634f;         // geom2
  } else if (h >= 6) {
    qscale = 1.0f;                                // geom1: raw dot needed
  }
#pragma unroll
  for (int e = 0; e < 16; ++e) qr[e] *= qscale;
  if (seg == 0) {
    const int idx = b * 32768 + h * 2048 + t;
    float oq = sq, ok = sk;
    if (h >= 6 && h < 10) {
      const float invc = 1.0f / curvg[h - 6];
      oq = sqrtf(invc + sq);
      ok = sqrtf(invc + sk);
    }
    qq[idx] = oq;
    kk[idx] = ok;
  }
  const int st = seg >> 1;
  const int quadA = (seg * 2) & 3, quadB = (seg * 2 + 1) & 3;
  {
    unsigned int wh[8], wl[8];
#pragma unroll
    for (int p = 0; p < 8; ++p) {
      unsigned short h0 = f2bf(qr[2*p]), h1 = f2bf(qr[2*p+1]);
      unsigned short l0 = f2bf(qr[2*p] - bf2f(h0)), l1 = f2bf(qr[2*p+1] - bf2f(h1));
      wh[p] = (unsigned)h0 | ((unsigned)h1 << 16);
      wl[p] = (unsigned)l0 | ((unsigned)l1 << 16);
    }
    const int qi = (t >> 4) & 1, c15q = t & 15;
    unsigned short* qs = Q2 + ((size_t)bh * 64 + (t >> 5)) * 4096;
    const int fh = ((qi * 2 + st) * 2 + 0) * 512, fl = fh + 512;
    *(uint4*)(qs + fh + quadA * 128 + c15q * 8) = uint4{wh[0], wh[1], wh[2], wh[3]};
    *(uint4*)(qs + fh + quadB * 128 + c15q * 8) = uint4{wh[4], wh[5], wh[6], wh[7]};
    *(uint4*)(qs + fl + quadA * 128 + c15q * 8) = uint4{wl[0], wl[1], wl[2], wl[3]};
    *(uint4*)(qs + fl + quadB * 128 + c15q * 8) = uint4{wl[4], wl[5], wl[6], wl[7]};
    // K: hi frags only
#pragma unroll
    for (int p = 0; p < 8; ++p) {
      unsigned short h0 = f2bf(kr[2*p]), h1 = f2bf(kr[2*p+1]);
      wh[p] = (unsigned)h0 | ((unsigned)h1 << 16);
    }
    const int kj = (tr >> 4) & 3, c15k = tr & 15;
    unsigned short* ks = K2 + ((size_t)bh * 32 + ttile) * 4096;
    const int gh = (st * 4 + kj) * 512;
    *(uint4*)(ks + gh + quadA * 128 + c15k * 8) = uint4{wh[0], wh[1], wh[2], wh[3]};
    *(uint4*)(ks + gh + quadB * 128 + c15k * 8) = uint4{wh[4], wh[5], wh[6], wh[7]};
  }
#pragma unroll
  for (int e = 0; e < 16; ++e) Vl[(seg * 16 + e) * 66 + tr] = f2bf(vv[e]);
  __syncthreads();
  {
    const int d = tid >> 2, tch = (tid & 3) * 16;
    unsigned int wv2[8];
#pragma unroll
    for (int p = 0; p < 8; ++p) {
      const unsigned short a0 = Vl[d * 66 + tch + 2*p];
      const unsigned short a1 = Vl[d * 66 + tch + 2*p + 1];
      wv2[p] = (unsigned)a0 | ((unsigned)a1 << 16);
    }
    const int dj = d >> 4, c15v = d & 15;
    const int ks2 = tch >> 5;
    const int qvA = (tch >> 3) & 3, qvB = ((tch >> 3) + 1) & 3;
    unsigned short* vs = V2 + ((size_t)bh * 32 + ttile) * 4096 + (ks2 * 4 + dj) * 512;
    *(uint4*)(vs + qvA * 128 + c15v * 8) = uint4{wv2[0], wv2[1], wv2[2], wv2[3]};
    *(uint4*)(vs + qvB * 128 + c15v * 8) = uint4{wv2[4], wv2[5], wv2[6], wv2[7]};
  }
}

// Split-K barrier-free MFMA flash attention (chunk=16, R25).
// Task u in [0,96) per bh: u<32 -> (qw=32+u, kt 0..15); u in [32,64) ->
// (qw=63-(u-32), kt 16..nkt-1, sizes 16..1 desc); u in [64,96) ->
// (qw=31-(u-64), kt 0..nkt-1, sizes 16..1 desc). z = u*32 + bh (u-major:
// WG's 4 waves share u -> equal size; ascending u = big-first; 3 uniform
// dispatch rounds of 1024). Swapped QK^T; in-reg softmax; P via ds_bpermute;
// K/V time-shared kv[2][4] buffer. Chain-bound floor ~88us (PARKED).
__global__ __launch_bounds__(256, 2) void attn_part(
    const unsigned short* __restrict__ Q2, const unsigned short* __restrict__ K2,
    const unsigned short* __restrict__ V2, const float* __restrict__ tqq,
    const float* __restrict__ tkk, const float* __restrict__ curvg,
    float* __restrict__ part) {
  const int tid = threadIdx.x;
  const int lane = tid & 63;
  const int wv = tid >> 6;
  const int quad = lane >> 4, c15 = lane & 15;
  const int z = blockIdx.x * 4 + wv;
  const int u = z >> 5;                 // 0..95, big-first
  const int bh = z & 31;
  int qw, ktB;
  if (u < 32)      { qw = 32 + u;        ktB = 0;  }
  else if (u < 64) { qw = 63 - (u - 32); ktB = 16; }
  else             { qw = 31 - (u - 64); ktB = 0;  }
  const int nkt = (qw >> 1) + 1;
  const int ktE = (u < 32) ? 16 : nkt;
  const int h = bh & 15;
  const int geom = (h < 6) ? 0 : ((h < 10) ? 1 : 2);
  const int qrow0 = qw * 32;
  const f32x4 zero4 = {0.f, 0.f, 0.f, 0.f};

  const unsigned short* qbase = Q2 + ((size_t)bh * 64 + qw) * 4096;
  bf16x8 qh[2][2], ql[2][2];
#pragma unroll
  for (int qi = 0; qi < 2; ++qi)
#pragma unroll
    for (int st = 0; st < 2; ++st) {
      const int f = ((qi * 2 + st) * 2) * 512 + lane * 8;
      qh[qi][st] = *(const bf16x8*)(qbase + f);
      ql[qi][st] = *(const bf16x8*)(qbase + f + 512);
    }

  float curv = 1.f, sic = 1.f;
  const float Moff = 4.0f;               // geom1 only
  float tqs[2] = {0.f, 0.f};             // tq per-lane scalar (q = c15)
  if (geom == 1) {
    curv = curvg[h - 6];
    sic = sqrtf(1.0f / curv);
#pragma unroll
    for (int qi = 0; qi < 2; ++qi)
      tqs[qi] = tqq[bh * 2048 + qrow0 + qi * 16 + c15];
  }

  const __bf16 one_b = (__bf16)1.0f;
  const bf16x8 ones = {one_b, one_b, one_b, one_b, one_b, one_b, one_b, one_b};

  const int iA = ((quad & 1) * 32 + c15) * 4;
  const int iB = iA + 64;
  const bool hiq = (quad >= 2);

  f32x4 o[2][4];
  f32x4 ol[2] = {zero4, zero4};
#pragma unroll
  for (int qi = 0; qi < 2; ++qi)
#pragma unroll
    for (int dj = 0; dj < 4; ++dj) o[qi][dj] = zero4;

  for (int kt = ktB; kt < ktE; ++kt) {
    const int kb = kt * 64;
    const unsigned short* kbase = K2 + ((size_t)bh * 32 + kt) * 4096;  // hi-only
    const unsigned short* vbase = V2 + ((size_t)bh * 32 + kt) * 4096;

    // ---- time-shared K/V register buffer: K phase
    bf16x8 kv[2][4];
#pragma unroll
    for (int st = 0; st < 2; ++st)
#pragma unroll
      for (int kj = 0; kj < 4; ++kj)
        kv[st][kj] = *(const bf16x8*)(kbase + (st * 4 + kj) * 512 + lane * 8);
    f32x4 tk4[4];
    if (geom == 1) {
#pragma unroll
      for (int kj = 0; kj < 4; ++kj)
        tk4[kj] = *(const f32x4*)(tkk + bh * 2048 + kb + kj * 16 + quad * 4);
    }

    // ---- S^T = K·(Qh+Ql)^T
    f32x4 s[2][4];
#pragma unroll
    for (int qi = 0; qi < 2; ++qi)
#pragma unroll
      for (int kj = 0; kj < 4; ++kj) s[qi][kj] = zero4;
    __builtin_amdgcn_s_setprio(1);
#pragma unroll
    for (int st = 0; st < 2; ++st) {
#pragma unroll
      for (int kj = 0; kj < 4; ++kj) {
#pragma unroll
        for (int qi = 0; qi < 2; ++qi) {
          s[qi][kj] = __builtin_amdgcn_mfma_f32_16x16x32_bf16(kv[st][kj], qh[qi][st], s[qi][kj], 0, 0, 0);
          s[qi][kj] = __builtin_amdgcn_mfma_f32_16x16x32_bf16(kv[st][kj], ql[qi][st], s[qi][kj], 0, 0, 0);
        }
      }
    }
    __builtin_amdgcn_s_setprio(0);

    // ---- V phase: overwrite kv (K dead after QK); loads fly under softmax
#pragma unroll
    for (int ks2 = 0; ks2 < 2; ++ks2)
#pragma unroll
      for (int dj = 0; dj < 4; ++dj)
        kv[ks2][dj] = *(const bf16x8*)(vbase + (ks2 * 4 + dj) * 512 + lane * 8);

    // ---- softmax in registers -> packed bf16 pairs
    const bool needmask = (kt == nkt - 1);
    unsigned pw[2][4][2];
#pragma unroll
    for (int qi = 0; qi < 2; ++qi) {
      const int qcol = qrow0 + qi * 16 + c15;
#pragma unroll
      for (int kj = 0; kj < 4; ++kj) {
        const int kloc = kb + kj * 16 + quad * 4;
        const f32x4 d4 = s[qi][kj];
        f32x4 p;
        if (geom == 1) {
          const float tq = tqs[qi];
#pragma unroll
          for (int r = 0; r < 4; ++r) {
            const float a = fmaxf(curv * (tq * tk4[kj][r] - d4[r]), 1.0f + 1e-7f);
            const float dis = sic * __logf(a + sqrtf(a * a - 1.0f));
            p[r] = __expf(__builtin_amdgcn_rcpf(1e-6f + dis) - Moff);
          }
        } else {
#pragma unroll
          for (int r = 0; r < 4; ++r) p[r] = exp2f(d4[r]);
        }
        if (needmask) {
#pragma unroll
          for (int r = 0; r < 4; ++r)
            if (kloc + r > qcol) p[r] = 0.0f;
        }
        union { float f; unsigned u2; } b0, b1, b2, b3;
        b0.f = p[0]; b1.f = p[1]; b2.f = p[2]; b3.f = p[3];
        pw[qi][kj][0] = (b0.u2 >> 16) | (b1.u2 & 0xffff0000u);
        pw[qi][kj][1] = (b2.u2 >> 16) | (b3.u2 & 0xffff0000u);
      }
    }

    // ---- PV via bpermute-assembled P fragments (kv now holds V)
    __builtin_amdgcn_s_setprio(1);
#pragma unroll
    for (int ks2 = 0; ks2 < 2; ++ks2) {
      const int a = ks2 * 2, b2 = ks2 * 2 + 1;
#pragma unroll
      for (int qi = 0; qi < 2; ++qi) {
        const int w0A = __builtin_amdgcn_ds_bpermute(iA, (int)pw[qi][a][0]);
        const int w0B = __builtin_amdgcn_ds_bpermute(iA, (int)pw[qi][b2][0]);
        const int w1A = __builtin_amdgcn_ds_bpermute(iA, (int)pw[qi][a][1]);
        const int w1B = __builtin_amdgcn_ds_bpermute(iA, (int)pw[qi][b2][1]);
        const int w2A = __builtin_amdgcn_ds_bpermute(iB, (int)pw[qi][a][0]);
        const int w2B = __builtin_amdgcn_ds_bpermute(iB, (int)pw[qi][b2][0]);
        const int w3A = __builtin_amdgcn_ds_bpermute(iB, (int)pw[qi][a][1]);
        const int w3B = __builtin_amdgcn_ds_bpermute(iB, (int)pw[qi][b2][1]);
        union { uint4 u; bf16x8 v; } pf;
        pf.u.x = (unsigned)(hiq ? w0B : w0A);
        pf.u.y = (unsigned)(hiq ? w1B : w1A);
        pf.u.z = (unsigned)(hiq ? w2B : w2A);
        pf.u.w = (unsigned)(hiq ? w3B : w3A);
        const bf16x8 pfrag = pf.v;
        ol[qi] = __builtin_amdgcn_mfma_f32_16x16x32_bf16(ones, pfrag, ol[qi], 0, 0, 0);
#pragma unroll
        for (int dj = 0; dj < 4; ++dj)
          o[qi][dj] = __builtin_amdgcn_mfma_f32_16x16x32_bf16(kv[ks2][dj], pfrag, o[qi][dj], 0, 0, 0);
      }
    }
    __builtin_amdgcn_s_setprio(0);
  }

  // ---- partial write: slot = bh*96 + u, stride 2112 f32 (O^T layout, internal)
  float* slot = part + (size_t)(bh * 96 + u) * 2112;
#pragma unroll
  for (int qi = 0; qi < 2; ++qi)
#pragma unroll
    for (int dj = 0; dj < 4; ++dj)
      *(f32x4*)(slot + (qi * 4 + dj) * 256 + lane * 4) = o[qi][dj];
  if (quad == 0) {
#pragma unroll
    for (int qi = 0; qi < 2; ++qi)
      slot[2048 + qi * 16 + c15] = ol[qi][0];
  }
}

// Sum chunk partials (<=2 now), divide, LDS-transpose, write A'y [hi|lo].
// Slot map: qw>=32 -> {u=qw-32, u=32+(63-qw)}; qw<32 -> {u=64+(31-qw)}.
__global__ __launch_bounds__(256) void attn_reduce(
    const float* __restrict__ part, unsigned short* __restrict__ Ay) {
  __shared__ float Ol[4][32 * 65];
  const int tid = threadIdx.x;
  const int lane = tid & 63;
  const int wv = tid >> 6;
  float* Olw = &Ol[wv][0];
  const int quad = lane >> 4, c15 = lane & 15;
  const int z = blockIdx.x * 4 + wv, bh = z & 31, qw = 63 - (z >> 5);
  const int b = bh >> 4, h = bh & 15;
  const int ua = (qw >= 32) ? (qw - 32) : (64 + (31 - qw));
  const int ub = 32 + (63 - qw);          // valid only if qw>=32
  const float* slA = part + (size_t)(bh * 96 + ua) * 2112;
  const float* slB = part + (size_t)(bh * 96 + ub) * 2112;

  const f32x4 zero4 = {0.f, 0.f, 0.f, 0.f};
  f32x4 o[8];
  float ls[2] = {0.f, 0.f};
#pragma unroll
  for (int i = 0; i < 8; ++i) o[i] = zero4;
#pragma unroll
  for (int i = 0; i < 8; ++i) o[i] += *(const f32x4*)(slA + i * 256 + lane * 4);
#pragma unroll
  for (int qi = 0; qi < 2; ++qi) ls[qi] += slA[2048 + qi * 16 + c15];
  if (qw >= 32) {
#pragma unroll
    for (int i = 0; i < 8; ++i) o[i] += *(const f32x4*)(slB + i * 256 + lane * 4);
#pragma unroll
    for (int qi = 0; qi < 2; ++qi) ls[qi] += slB[2048 + qi * 16 + c15];
  }
#pragma unroll
  for (int qi = 0; qi < 2; ++qi) {
    const float invl = __builtin_amdgcn_rcpf(ls[qi]);
#pragma unroll
    for (int dj = 0; dj < 4; ++dj) {
      const f32x4 val = o[qi * 4 + dj] * invl;
#pragma unroll
      for (int r = 0; r < 4; ++r)
        Olw[(qi * 16 + c15) * 65 + dj * 16 + quad * 4 + r] = val[r];
    }
  }
  __syncthreads();
  const int row = lane >> 1, half = lane & 1;
  const float* rp = Olw + row * 65 + half * 32;
  unsigned int uh[16], ul2[16];
#pragma unroll
  for (int p = 0; p < 16; ++p) {
    const float v0 = rp[2 * p], v1 = rp[2 * p + 1];
    const unsigned short h0 = f2bf(v0), h1 = f2bf(v1);
    const unsigned short g0 = f2bf(v0 - bf2f(h0)), g1 = f2bf(v1 - bf2f(h1));
    uh[p] = (unsigned)h0 | ((unsigned)h1 << 16);
    ul2[p] = (unsigned)g0 | ((unsigned)g1 << 16);
  }
  unsigned short* yp = Ay + ((size_t)(b * 2048 + qw * 32 + row)) * 2048 + h * 64 + half * 32;
#pragma unroll
  for (int c = 0; c < 4; ++c) {
    *(uint4*)(yp + 8 * c)        = uint4{uh[4*c], uh[4*c+1], uh[4*c+2], uh[4*c+3]};
    *(uint4*)(yp + 1024 + 8 * c) = uint4{ul2[4*c], ul2[4*c+1], ul2[4*c+2], ul2[4*c+3]};
  }
}

extern "C" void kernel_launch(void* const* d_in, const int* in_sizes, int n_in,
                              void* d_out, int out_size, void* d_ws, size_t ws_size,
                              hipStream_t stream) {
  const float* x      = (const float*)d_in[0];
  const float* qkv_w  = (const float*)d_in[1];
  const float* proj_w = (const float*)d_in[2];
  const float* proj_b = (const float*)d_in[3];
  const float* curvature = (const float*)d_in[4];
  float* out = (float*)d_out;

  char* ws = (char*)d_ws;
  unsigned short* AX   = (unsigned short*)ws;                     // 4096x2048 bf16 hi|lo
  unsigned short* BW1  = (unsigned short*)(ws + 16777216);        // 3072x1024 bf16 hi
  float*          QKVF = (float*)(ws + 33554432);                 // 4096x3072 f32
  unsigned short* BPW1 = (unsigned short*)(ws + 83886080);        // 1024x1024 bf16 hi
  unsigned short* Q2   = (unsigned short*)ws;                     // 16MB
  unsigned short* K2   = (unsigned short*)(ws + 16777216);        // 8MB (hi-only)
  unsigned short* V2   = (unsigned short*)(ws + 25165824);        // 8MB
  float*          PART = (float*)(ws + 33554432);                 // 25,952,256 B
  unsigned short* AY   = (unsigned short*)ws;                     // 4096x2048 bf16 hi|lo
  float*          QQ   = (float*)(ws + 94371840);
  float*          KK   = (float*)(ws + 94633984);

  // one fused launch: x->AX, qkv_w->BW1, proj_w->BPW1 (BPW1 region free in
  // both phases: [83886080, 85983232) after QKVF's end, before QQ).
  split_all<<<8192, 256, 0, stream>>>(x, qkv_w, proj_w, AX, BW1, BPW1);

  // M=4096 N=3072 Kr=1024: 32x24 = 768 wgs (768%8==0 for XCD swizzle).
  // loN=2048: V-third tiles (n0>=2048) skip the lo product.
  gemm_bt2<0><<<768, 256, 0, stream>>>(AX, BW1, QKVF, nullptr, 24, 3072, 1024, 2048);

  prep<<<1024, 256, 0, stream>>>(QKVF, Q2, K2, V2, QQ, KK, curvature);

  // chunk=16 split-K: 3072 wave-tasks = 768 WGs.
  attn_part<<<768, 256, 0, stream>>>(Q2, K2, V2, QQ, KK, curvature, PART);

  attn_reduce<<<512, 256, 0, stream>>>(PART, AY);

  // M=4096 N=1024 Kr=1024: 32x8 = 256 wgs; loN=N_ -> never skip lo.
  gemm_bt2<1><<<256, 256, 0, stream>>>(AY, BPW1, out, proj_b, 8, 1024, 1024, 1024);
}

// Round 13
// 259.735 us; speedup vs baseline: 1.0793x; 1.0793x over previous
//
#include <hip/hip_runtime.h>
#include <stdint.h>
#include <math.h>

// MultiGeometryAttention — f32 in/out. B=2 T=2048 C=1024 H=16 HD=64.
// heads 0-5 sdpa(0.125) | 6-9 hyperbolic(curvature) | 10-15 cos-normalized sdpa(8).
// History: R13 316. R16 287 (attn reg-batch loads -> 88us). R20 285 (swapped
// QK^T, in-reg P, LDS->0). R21 278 (B hi-only GEMM + XCD swizzle). R22 FAILED
// (no-split-K: serial chain). R23 266.9 (gemm0 V-third lo-skip). R24 264.0 =
// BEST (K/V reg time-share). R25 FAILED (280: chunk-16 tail granularity 2x ->
// occupancy 12.5->9.8; "dispatch rounds" are a fiction — hw schedules greedily;
// chunk-8's 5120 fine tasks ARE what keeps CUs full).
// R26: recovery. attn_part/attn_reduce/PART restored byte-for-byte from R24
// (chunk-8, 160 slots/bh). Kept from R25 only the safe piece: fused split_all
// launch (x->AX, qkv_w->BW1, proj_w->BPW1; BPW1 at ws[83886080), free in both
// phases). attn is PARKED: 6 experiments null/neg; chain-bound 88us floor at
// ~1 wave/SIMD. Predict total ~261.
// WS (proven peak 94,896,128 B):
//  phase1: AX[0,16777216) BW1[16777216,23068672) | QKVF[33554432,83886080)
//          BPW1[83886080,85983232)
//  post-prep: Q2[0,16777216) K2hi[16777216,25165824) V2[25165824,33554432)
//             PART[33554432,76808192) BPW1[83886080,85983232)
//  post-attn: AY[0,16777216) | QQ[94371840) KK[94633984)

typedef __bf16 bf16x8 __attribute__((ext_vector_type(8)));
typedef float f32x4 __attribute__((ext_vector_type(4)));

static __device__ __forceinline__ float bf2f(unsigned short u) {
  union { unsigned int i; float f; } v; v.i = ((unsigned int)u) << 16; return v.f;
}
static __device__ __forceinline__ unsigned short f2bf(float f) {
  union { float f; unsigned int i; } v; v.f = f;
  unsigned int x = v.i;
  x += 0x7fffu + ((x >> 16) & 1u);   // RNE
  return (unsigned short)(x >> 16);
}

// direct global->LDS async copy, 16B/lane (gemm staging only).
static __device__ __forceinline__ void async_copy16(const void* gsrc, void* ldst) {
  auto* lp = reinterpret_cast<__attribute__((address_space(3))) unsigned int*>(
      reinterpret_cast<uintptr_t>(ldst));
  auto* gp = reinterpret_cast<const __attribute__((address_space(1))) unsigned int*>(
      reinterpret_cast<uintptr_t>(gsrc));
  __builtin_amdgcn_global_load_lds(gp, lp, 16, 0, 0);
}

// Fused input splitting (one launch):
//  blocks [0,4096):       x      -> AX   [hi|lo] 2048-wide
//  blocks [4096,7168):    qkv_w  -> BW1  hi-only 1024-wide
//  blocks [7168,8192):    proj_w -> BPW1 hi-only 1024-wide
__global__ __launch_bounds__(256) void split_all(
    const float* __restrict__ x, const float* __restrict__ qkv_w,
    const float* __restrict__ proj_w, unsigned short* __restrict__ AX,
    unsigned short* __restrict__ BW1, unsigned short* __restrict__ BPW1) {
  const int bid = blockIdx.x;
  const int kq = threadIdx.x * 4;
  if (bid < 4096) {
    const int row = bid;
    const f32x4 v = *(const f32x4*)(x + (size_t)row * 1024 + kq);
    unsigned short hi[4], lo[4];
#pragma unroll
    for (int i = 0; i < 4; ++i) {
      hi[i] = f2bf(v[i]);
      lo[i] = f2bf(v[i] - bf2f(hi[i]));   // exact residual in f32
    }
    uint2 uh, ul;
    uh.x = (unsigned)hi[0] | ((unsigned)hi[1] << 16);
    uh.y = (unsigned)hi[2] | ((unsigned)hi[3] << 16);
    ul.x = (unsigned)lo[0] | ((unsigned)lo[1] << 16);
    ul.y = (unsigned)lo[2] | ((unsigned)lo[3] << 16);
    unsigned short* op = AX + (size_t)row * 2048 + kq;
    *(uint2*)(op)        = uh;
    *(uint2*)(op + 1024) = ul;
  } else {
    const bool isq = (bid < 7168);
    const int row = isq ? (bid - 4096) : (bid - 7168);
    const float* src = isq ? qkv_w : proj_w;
    unsigned short* dst = isq ? BW1 : BPW1;
    const f32x4 v = *(const f32x4*)(src + (size_t)row * 1024 + kq);
    uint2 uh;
    uh.x = (unsigned)f2bf(v[0]) | ((unsigned)f2bf(v[1]) << 16);
    uh.y = (unsigned)f2bf(v[2]) | ((unsigned)f2bf(v[3]) << 16);
    *(uint2*)(dst + (size_t)row * 1024 + kq) = uh;
  }
}

// C[m][n] = sum_k (Ahi[m][k]+Alo[m][k])*B[n][k] (+bias[n]) -> f32.
// A: [M][2*Kr] hi|lo. B: [N][Kr] hi-only. 128x128 tile, BK=64 real-k, 4 waves,
// two MFMAs per frag pair. XOR-swizzled LDS. Bijective XCD swizzle (nwg%8==0).
// Tiles with n0 >= loN skip the lo product entirely (V-third of gemm0: output
// is bf16-truncated downstream, lo contribution below truncation error).
template <int HASBIAS>
__global__ __launch_bounds__(256) void gemm_bt2(
    const unsigned short* __restrict__ A, const unsigned short* __restrict__ Bm,
    float* __restrict__ C, const float* __restrict__ bias,
    int NX, int N_, int Kr, int loN) {
  alignas(16) __shared__ unsigned short smAh[128 * 64];
  alignas(16) __shared__ unsigned short smAl[128 * 64];
  alignas(16) __shared__ unsigned short smB [128 * 64];
  const int tid = threadIdx.x;
  const int lane = tid & 63;
  const int wvi = tid >> 6;
  const int wm = wvi >> 1, wn = wvi & 1;
  const int cpx = gridDim.x >> 3;
  const int wgid = ((int)blockIdx.x & 7) * cpx + ((int)blockIdx.x >> 3);
  const long m0 = (long)(wgid / NX) * 128, n0 = (long)(wgid % NX) * 128;
  const int K2w = Kr * 2;
  const bool skiplo = (n0 >= (long)loN);   // wave-uniform

  const f32x4 zero4 = {0.f, 0.f, 0.f, 0.f};
  f32x4 acc[4][4];
#pragma unroll
  for (int i = 0; i < 4; ++i)
#pragma unroll
    for (int j = 0; j < 4; ++j) acc[i][j] = zero4;

  int mrow[4], gg[4];
#pragma unroll
  for (int w = 0; w < 4; ++w) {
    int c = w * 256 + tid;
    mrow[w] = c >> 3;
    gg[w] = (c & 7) ^ ((c >> 3) & 7);
  }

  const int kTiles = Kr >> 6;
  for (int kt = 0; kt < kTiles; ++kt) {
    if (kt) __syncthreads();
    const int kb = kt << 6;
#pragma unroll
    for (int w = 0; w < 4; ++w) {
      const int c = w * 256 + tid;
      const size_t arow = (size_t)(m0 + mrow[w]) * K2w + kb + gg[w] * 8;
      async_copy16(A + arow,        (char*)smAh + c * 16);
      if (!skiplo)
        async_copy16(A + arow + Kr, (char*)smAl + c * 16);
      async_copy16(Bm + (size_t)(n0 + mrow[w]) * Kr + kb + gg[w] * 8,
                   (char*)smB + c * 16);
    }
    __syncthreads();
#pragma unroll
    for (int ks = 0; ks < 2; ++ks) {
      bf16x8 afh[4], afl[4], bg[4];
#pragma unroll
      for (int i = 0; i < 4; ++i) {
        const int ra = wm * 64 + i * 16 + (lane & 15);
        const int ga = (ks * 4 + (lane >> 4)) ^ (ra & 7);
        afh[i] = *(const bf16x8*)((const char*)smAh + ra * 128 + ga * 16);
        if (!skiplo)
          afl[i] = *(const bf16x8*)((const char*)smAl + ra * 128 + ga * 16);
        const int rb = wn * 64 + i * 16 + (lane & 15);
        const int gb2 = (ks * 4 + (lane >> 4)) ^ (rb & 7);
        bg[i] = *(const bf16x8*)((const char*)smB + rb * 128 + gb2 * 16);
      }
#pragma unroll
      for (int i = 0; i < 4; ++i)
#pragma unroll
        for (int j = 0; j < 4; ++j) {
          acc[i][j] = __builtin_amdgcn_mfma_f32_16x16x32_bf16(afh[i], bg[j], acc[i][j], 0, 0, 0);
          if (!skiplo)
            acc[i][j] = __builtin_amdgcn_mfma_f32_16x16x32_bf16(afl[i], bg[j], acc[i][j], 0, 0, 0);
        }
    }
  }

  const int r0 = wm * 64 + (lane >> 4) * 4;
  const int c0 = wn * 64 + (lane & 15);
#pragma unroll
  for (int j = 0; j < 4; ++j) {
    const long col = n0 + c0 + j * 16;
    float bv = 0.f;
    if (HASBIAS) bv = bias[col];
#pragma unroll
    for (int i = 0; i < 4; ++i) {
#pragma unroll
      for (int r = 0; r < 4; ++r) {
        const long row = m0 + r0 + i * 16 + r;
        C[row * N_ + col] = acc[i][j][r] + bv;
      }
    }
  }
}

// prep: rotary q,k; norms; normalize h>=10; fold sscale*log2e into q (geom0/2);
// emit fragment-linear tiles. Q2: [hi|lo] 8 frags/qw. K2: hi-only 8 frags/ktile.
// V2: 8 frags/ktile.
__global__ __launch_bounds__(256) void prep(
    const float* __restrict__ qkvf, unsigned short* __restrict__ Q2,
    unsigned short* __restrict__ K2, unsigned short* __restrict__ V2,
    float* __restrict__ qq, float* __restrict__ kk, const float* __restrict__ curvg) {
  __shared__ unsigned short Vl[64 * 66];
  const int tid = threadIdx.x;
  const int zz = blockIdx.x;
  const int ttile = zz & 31, bh = zz >> 5;
  const int b = bh >> 4, h = bh & 15;
  const int t0 = ttile * 64;
  const int tr = tid >> 2, seg = tid & 3;
  const int t = t0 + tr;
  const float* src = qkvf + ((size_t)(b * 2048 + t)) * 3072 + h * 64 + seg * 16;

  float qv[16], kv[16], vv[16];
#pragma unroll
  for (int c = 0; c < 4; ++c) {
    const f32x4 a  = *(const f32x4*)(src + c * 4);
    const f32x4 bb = *(const f32x4*)(src + 1024 + c * 4);
    const f32x4 cc = *(const f32x4*)(src + 2048 + c * 4);
#pragma unroll
    for (int e = 0; e < 4; ++e) { qv[c*4+e] = a[e]; kv[c*4+e] = bb[e]; vv[c*4+e] = cc[e]; }
  }
  float qr[16], kr[16];
#pragma unroll
  for (int e = 0; e < 16; ++e) {
    const int d = seg * 16 + e;
    const int i = d & 31;
    const float invf = exp2f(-0.41524101186109286f * (float)i);  // 10000^(-i/32)
    float sn, cs;
    sincosf((float)t * invf, &sn, &cs);
    const float qo = __shfl_xor(qv[e], 2, 64);
    const float ko = __shfl_xor(kv[e], 2, 64);
    qr[e] = (d < 32) ? (qv[e] * cs + qo * sn) : (qv[e] * cs - qo * sn);
    kr[e] = (d < 32) ? (kv[e] * cs + ko * sn) : (kv[e] * cs - ko * sn);
  }
  float sq = 0.f, sk = 0.f;
#pragma unroll
  for (int e = 0; e < 16; ++e) { sq += qr[e] * qr[e]; sk += kr[e] * kr[e]; }
  sq += __shfl_xor(sq, 1, 64); sq += __shfl_xor(sq, 2, 64);
  sk += __shfl_xor(sk, 1, 64); sk += __shfl_xor(sk, 2, 64);
  float qscale = 0.125f * 1.4426950408889634f;   // geom0: fold sscale*log2e
  if (h >= 10) {
    const float rq = 1.0f / fmaxf(sqrtf(sq), 1e-12f);
    const float rk = 1.0f / fmaxf(sqrtf(sk), 1e-12f);
#pragma unroll
    for (int e = 0; e < 16; ++e) { qr[e] *= rq; kr[e] *= rk; }
    qscale = 8.0f * 1.4426950408889634f;         // geom2
  } else if (h >= 6) {
    qscale = 1.0f;                                // geom1: raw dot needed
  }
#pragma unroll
  for (int e = 0; e < 16; ++e) qr[e] *= qscale;
  if (seg == 0) {
    const int idx = b * 32768 + h * 2048 + t;
    float oq = sq, ok = sk;
    if (h >= 6 && h < 10) {
      const float invc = 1.0f / curvg[h - 6];
      oq = sqrtf(invc + sq);
      ok = sqrtf(invc + sk);
    }
    qq[idx] = oq;
    kk[idx] = ok;
  }
  const int st = seg >> 1;
  const int quadA = (seg * 2) & 3, quadB = (seg * 2 + 1) & 3;
  {
    unsigned int wh[8], wl[8];
#pragma unroll
    for (int p = 0; p < 8; ++p) {
      unsigned short h0 = f2bf(qr[2*p]), h1 = f2bf(qr[2*p+1]);
      unsigned short l0 = f2bf(qr[2*p] - bf2f(h0)), l1 = f2bf(qr[2*p+1] - bf2f(h1));
      wh[p] = (unsigned)h0 | ((unsigned)h1 << 16);
      wl[p] = (unsigned)l0 | ((unsigned)l1 << 16);
    }
    const int qi = (t >> 4) & 1, c15q = t & 15;
    unsigned short* qs = Q2 + ((size_t)bh * 64 + (t >> 5)) * 4096;
    const int fh = ((qi * 2 + st) * 2 + 0) * 512, fl = fh + 512;
    *(uint4*)(qs + fh + quadA * 128 + c15q * 8) = uint4{wh[0], wh[1], wh[2], wh[3]};
    *(uint4*)(qs + fh + quadB * 128 + c15q * 8) = uint4{wh[4], wh[5], wh[6], wh[7]};
    *(uint4*)(qs + fl + quadA * 128 + c15q * 8) = uint4{wl[0], wl[1], wl[2], wl[3]};
    *(uint4*)(qs + fl + quadB * 128 + c15q * 8) = uint4{wl[4], wl[5], wl[6], wl[7]};
    // K: hi frags only
#pragma unroll
    for (int p = 0; p < 8; ++p) {
      unsigned short h0 = f2bf(kr[2*p]), h1 = f2bf(kr[2*p+1]);
      wh[p] = (unsigned)h0 | ((unsigned)h1 << 16);
    }
    const int kj = (tr >> 4) & 3, c15k = tr & 15;
    unsigned short* ks = K2 + ((size_t)bh * 32 + ttile) * 4096;
    const int gh = (st * 4 + kj) * 512;
    *(uint4*)(ks + gh + quadA * 128 + c15k * 8) = uint4{wh[0], wh[1], wh[2], wh[3]};
    *(uint4*)(ks + gh + quadB * 128 + c15k * 8) = uint4{wh[4], wh[5], wh[6], wh[7]};
  }
#pragma unroll
  for (int e = 0; e < 16; ++e) Vl[(seg * 16 + e) * 66 + tr] = f2bf(vv[e]);
  __syncthreads();
  {
    const int d = tid >> 2, tch = (tid & 3) * 16;
    unsigned int wv2[8];
#pragma unroll
    for (int p = 0; p < 8; ++p) {
      const unsigned short a0 = Vl[d * 66 + tch + 2*p];
      const unsigned short a1 = Vl[d * 66 + tch + 2*p + 1];
      wv2[p] = (unsigned)a0 | ((unsigned)a1 << 16);
    }
    const int dj = d >> 4, c15v = d & 15;
    const int ks2 = tch >> 5;
    const int qvA = (tch >> 3) & 3, qvB = ((tch >> 3) + 1) & 3;
    unsigned short* vs = V2 + ((size_t)bh * 32 + ttile) * 4096 + (ks2 * 4 + dj) * 512;
    *(uint4*)(vs + qvA * 128 + c15v * 8) = uint4{wv2[0], wv2[1], wv2[2], wv2[3]};
    *(uint4*)(vs + qvB * 128 + c15v * 8) = uint4{wv2[4], wv2[5], wv2[6], wv2[7]};
  }
}

// Split-K barrier-free MFMA flash attention (R24 form, chunk=8 — the balancer).
// Swapped QK^T (sT=mfma(K,Q)); softmax in registers; P via ds_bpermute;
// K/V time-share one kv[2][4] register buffer; bh-major, big-(qw,ch)-first.
__global__ __launch_bounds__(256, 2) void attn_part(
    const unsigned short* __restrict__ Q2, const unsigned short* __restrict__ K2,
    const unsigned short* __restrict__ V2, const float* __restrict__ tqq,
    const float* __restrict__ tkk, const float* __restrict__ curvg,
    float* __restrict__ part) {
  const int tid = threadIdx.x;
  const int lane = tid & 63;
  const int wv = tid >> 6;
  const int quad = lane >> 4, c15 = lane & 15;
  const int z = blockIdx.x * 4 + wv;
  const int bh = z / 160;                // bh-major
  const int u = 159 - (z - bh * 160);    // big (qw,ch) first within the head
  int qw, ch;
  if (u < 16)      { qw = u; ch = 0; }
  else if (u < 48) { qw = 16 + ((u - 16) >> 1); ch = (u - 16) & 1; }
  else if (u < 96) { const int s2 = u - 48; const int q3 = s2 / 3; qw = 32 + q3; ch = s2 - 3 * q3; }
  else             { const int s2 = u - 96; qw = 48 + (s2 >> 2); ch = s2 & 3; }
  const int h = bh & 15;
  const int geom = (h < 6) ? 0 : ((h < 10) ? 1 : 2);
  const int qrow0 = qw * 32;
  const f32x4 zero4 = {0.f, 0.f, 0.f, 0.f};

  const unsigned short* qbase = Q2 + ((size_t)bh * 64 + qw) * 4096;
  bf16x8 qh[2][2], ql[2][2];
#pragma unroll
  for (int qi = 0; qi < 2; ++qi)
#pragma unroll
    for (int st = 0; st < 2; ++st) {
      const int f = ((qi * 2 + st) * 2) * 512 + lane * 8;
      qh[qi][st] = *(const bf16x8*)(qbase + f);
      ql[qi][st] = *(const bf16x8*)(qbase + f + 512);
    }

  float curv = 1.f, sic = 1.f;
  const float Moff = 4.0f;               // geom1 only
  float tqs[2] = {0.f, 0.f};             // tq per-lane scalar (q = c15)
  if (geom == 1) {
    curv = curvg[h - 6];
    sic = sqrtf(1.0f / curv);
#pragma unroll
    for (int qi = 0; qi < 2; ++qi)
      tqs[qi] = tqq[bh * 2048 + qrow0 + qi * 16 + c15];
  }

  const __bf16 one_b = (__bf16)1.0f;
  const bf16x8 ones = {one_b, one_b, one_b, one_b, one_b, one_b, one_b, one_b};

  const int iA = ((quad & 1) * 32 + c15) * 4;
  const int iB = iA + 64;
  const bool hiq = (quad >= 2);

  f32x4 o[2][4];
  f32x4 ol[2] = {zero4, zero4};
#pragma unroll
  for (int qi = 0; qi < 2; ++qi)
#pragma unroll
    for (int dj = 0; dj < 4; ++dj) o[qi][dj] = zero4;

  const int nkt = (qw >> 1) + 1;
  const int ktB = ch * 8;
  const int ktE = (ktB + 8 < nkt) ? (ktB + 8) : nkt;
  for (int kt = ktB; kt < ktE; ++kt) {
    const int kb = kt * 64;
    const unsigned short* kbase = K2 + ((size_t)bh * 32 + kt) * 4096;  // hi-only
    const unsigned short* vbase = V2 + ((size_t)bh * 32 + kt) * 4096;

    // ---- time-shared K/V register buffer: K phase
    bf16x8 kv[2][4];
#pragma unroll
    for (int st = 0; st < 2; ++st)
#pragma unroll
      for (int kj = 0; kj < 4; ++kj)
        kv[st][kj] = *(const bf16x8*)(kbase + (st * 4 + kj) * 512 + lane * 8);
    f32x4 tk4[4];
    if (geom == 1) {
#pragma unroll
      for (int kj = 0; kj < 4; ++kj)
        tk4[kj] = *(const f32x4*)(tkk + bh * 2048 + kb + kj * 16 + quad * 4);
    }

    // ---- S^T = K·(Qh+Ql)^T
    f32x4 s[2][4];
#pragma unroll
    for (int qi = 0; qi < 2; ++qi)
#pragma unroll
      for (int kj = 0; kj < 4; ++kj) s[qi][kj] = zero4;
    __builtin_amdgcn_s_setprio(1);
#pragma unroll
    for (int st = 0; st < 2; ++st) {
#pragma unroll
      for (int kj = 0; kj < 4; ++kj) {
#pragma unroll
        for (int qi = 0; qi < 2; ++qi) {
          s[qi][kj] = __builtin_amdgcn_mfma_f32_16x16x32_bf16(kv[st][kj], qh[qi][st], s[qi][kj], 0, 0, 0);
          s[qi][kj] = __builtin_amdgcn_mfma_f32_16x16x32_bf16(kv[st][kj], ql[qi][st], s[qi][kj], 0, 0, 0);
        }
      }
    }
    __builtin_amdgcn_s_setprio(0);

    // ---- V phase: overwrite kv (K dead after QK); loads fly under softmax
#pragma unroll
    for (int ks2 = 0; ks2 < 2; ++ks2)
#pragma unroll
      for (int dj = 0; dj < 4; ++dj)
        kv[ks2][dj] = *(const bf16x8*)(vbase + (ks2 * 4 + dj) * 512 + lane * 8);

    // ---- softmax in registers -> packed bf16 pairs
    const bool needmask = (kt == nkt - 1);
    unsigned pw[2][4][2];
#pragma unroll
    for (int qi = 0; qi < 2; ++qi) {
      const int qcol = qrow0 + qi * 16 + c15;
#pragma unroll
      for (int kj = 0; kj < 4; ++kj) {
        const int kloc = kb + kj * 16 + quad * 4;
        const f32x4 d4 = s[qi][kj];
        f32x4 p;
        if (geom == 1) {
          const float tq = tqs[qi];
#pragma unroll
          for (int r = 0; r < 4; ++r) {
            const float a = fmaxf(curv * (tq * tk4[kj][r] - d4[r]), 1.0f + 1e-7f);
            const float dis = sic * __logf(a + sqrtf(a * a - 1.0f));
            p[r] = __expf(__builtin_amdgcn_rcpf(1e-6f + dis) - Moff);
          }
        } else {
#pragma unroll
          for (int r = 0; r < 4; ++r) p[r] = exp2f(d4[r]);
        }
        if (needmask) {
#pragma unroll
          for (int r = 0; r < 4; ++r)
            if (kloc + r > qcol) p[r] = 0.0f;
        }
        union { float f; unsigned u2; } b0, b1, b2, b3;
        b0.f = p[0]; b1.f = p[1]; b2.f = p[2]; b3.f = p[3];
        pw[qi][kj][0] = (b0.u2 >> 16) | (b1.u2 & 0xffff0000u);
        pw[qi][kj][1] = (b2.u2 >> 16) | (b3.u2 & 0xffff0000u);
      }
    }

    // ---- PV via bpermute-assembled P fragments (kv now holds V)
    __builtin_amdgcn_s_setprio(1);
#pragma unroll
    for (int ks2 = 0; ks2 < 2; ++ks2) {
      const int a = ks2 * 2, b2 = ks2 * 2 + 1;
#pragma unroll
      for (int qi = 0; qi < 2; ++qi) {
        const int w0A = __builtin_amdgcn_ds_bpermute(iA, (int)pw[qi][a][0]);
        const int w0B = __builtin_amdgcn_ds_bpermute(iA, (int)pw[qi][b2][0]);
        const int w1A = __builtin_amdgcn_ds_bpermute(iA, (int)pw[qi][a][1]);
        const int w1B = __builtin_amdgcn_ds_bpermute(iA, (int)pw[qi][b2][1]);
        const int w2A = __builtin_amdgcn_ds_bpermute(iB, (int)pw[qi][a][0]);
        const int w2B = __builtin_amdgcn_ds_bpermute(iB, (int)pw[qi][b2][0]);
        const int w3A = __builtin_amdgcn_ds_bpermute(iB, (int)pw[qi][a][1]);
        const int w3B = __builtin_amdgcn_ds_bpermute(iB, (int)pw[qi][b2][1]);
        union { uint4 u; bf16x8 v; } pf;
        pf.u.x = (unsigned)(hiq ? w0B : w0A);
        pf.u.y = (unsigned)(hiq ? w1B : w1A);
        pf.u.z = (unsigned)(hiq ? w2B : w2A);
        pf.u.w = (unsigned)(hiq ? w3B : w3A);
        const bf16x8 pfrag = pf.v;
        ol[qi] = __builtin_amdgcn_mfma_f32_16x16x32_bf16(ones, pfrag, ol[qi], 0, 0, 0);
#pragma unroll
        for (int dj = 0; dj < 4; ++dj)
          o[qi][dj] = __builtin_amdgcn_mfma_f32_16x16x32_bf16(kv[ks2][dj], pfrag, o[qi][dj], 0, 0, 0);
      }
    }
    __builtin_amdgcn_s_setprio(0);
  }

  // ---- partial write: slot = bh*160 + u, stride 2112 f32 (O^T layout, internal)
  float* slot = part + (size_t)(bh * 160 + u) * 2112;
#pragma unroll
  for (int qi = 0; qi < 2; ++qi)
#pragma unroll
    for (int dj = 0; dj < 4; ++dj)
      *(f32x4*)(slot + (qi * 4 + dj) * 256 + lane * 4) = o[qi][dj];
  if (quad == 0) {
#pragma unroll
    for (int qi = 0; qi < 2; ++qi)
      slot[2048 + qi * 16 + c15] = ol[qi][0];
  }
}

// Sum chunk partials, divide, LDS-transpose, write A'y [hi|lo] (2048-wide).
// Slots hold O^T (elem r <-> d=dj*16+quad*4+r, q=qi*16+c15); l scalar per lane.
__global__ __launch_bounds__(256) void attn_reduce(
    const float* __restrict__ part, unsigned short* __restrict__ Ay) {
  __shared__ float Ol[4][32 * 65];
  const int tid = threadIdx.x;
  const int lane = tid & 63;
  const int wv = tid >> 6;
  float* Olw = &Ol[wv][0];
  const int quad = lane >> 4, c15 = lane & 15;
  const int z = blockIdx.x * 4 + wv, bh = z & 31, qw = 63 - (z >> 5);
  const int b = bh >> 4, h = bh & 15;
  const int G = qw >> 4;
  const int base = qw + 8 * G * (G - 1) + (qw & 15) * G;
  const float* slot0 = part + (size_t)(bh * 160 + base) * 2112;

  const f32x4 zero4 = {0.f, 0.f, 0.f, 0.f};
  f32x4 o[8];
  float ls[2] = {0.f, 0.f};
#pragma unroll
  for (int i = 0; i < 8; ++i) o[i] = zero4;
  for (int chv = 0; chv <= G; ++chv) {
    const float* sl = slot0 + chv * 2112;
#pragma unroll
    for (int i = 0; i < 8; ++i) o[i] += *(const f32x4*)(sl + i * 256 + lane * 4);
#pragma unroll
    for (int qi = 0; qi < 2; ++qi)
      ls[qi] += sl[2048 + qi * 16 + c15];
  }
#pragma unroll
  for (int qi = 0; qi < 2; ++qi) {
    const float invl = __builtin_amdgcn_rcpf(ls[qi]);
#pragma unroll
    for (int dj = 0; dj < 4; ++dj) {
      const f32x4 val = o[qi * 4 + dj] * invl;
#pragma unroll
      for (int r = 0; r < 4; ++r)
        Olw[(qi * 16 + c15) * 65 + dj * 16 + quad * 4 + r] = val[r];
    }
  }
  __syncthreads();
  const int row = lane >> 1, half = lane & 1;
  const float* rp = Olw + row * 65 + half * 32;
  unsigned int uh[16], ul2[16];
#pragma unroll
  for (int p = 0; p < 16; ++p) {
    const float v0 = rp[2 * p], v1 = rp[2 * p + 1];
    const unsigned short h0 = f2bf(v0), h1 = f2bf(v1);
    const unsigned short g0 = f2bf(v0 - bf2f(h0)), g1 = f2bf(v1 - bf2f(h1));
    uh[p] = (unsigned)h0 | ((unsigned)h1 << 16);
    ul2[p] = (unsigned)g0 | ((unsigned)g1 << 16);
  }
  unsigned short* yp = Ay + ((size_t)(b * 2048 + qw * 32 + row)) * 2048 + h * 64 + half * 32;
#pragma unroll
  for (int c = 0; c < 4; ++c) {
    *(uint4*)(yp + 8 * c)        = uint4{uh[4*c], uh[4*c+1], uh[4*c+2], uh[4*c+3]};
    *(uint4*)(yp + 1024 + 8 * c) = uint4{ul2[4*c], ul2[4*c+1], ul2[4*c+2], ul2[4*c+3]};
  }
}

extern "C" void kernel_launch(void* const* d_in, const int* in_sizes, int n_in,
                              void* d_out, int out_size, void* d_ws, size_t ws_size,
                              hipStream_t stream) {
  const float* x      = (const float*)d_in[0];
  const float* qkv_w  = (const float*)d_in[1];
  const float* proj_w = (const float*)d_in[2];
  const float* proj_b = (const float*)d_in[3];
  const float* curvature = (const float*)d_in[4];
  float* out = (float*)d_out;

  char* ws = (char*)d_ws;
  unsigned short* AX   = (unsigned short*)ws;                     // 4096x2048 bf16 hi|lo
  unsigned short* BW1  = (unsigned short*)(ws + 16777216);        // 3072x1024 bf16 hi
  float*          QKVF = (float*)(ws + 33554432);                 // 4096x3072 f32
  unsigned short* BPW1 = (unsigned short*)(ws + 83886080);        // 1024x1024 bf16 hi
  unsigned short* Q2   = (unsigned short*)ws;                     // 16MB
  unsigned short* K2   = (unsigned short*)(ws + 16777216);        // 8MB (hi-only)
  unsigned short* V2   = (unsigned short*)(ws + 25165824);        // 8MB
  float*          PART = (float*)(ws + 33554432);                 // 43,253,760 B
  unsigned short* AY   = (unsigned short*)ws;                     // 4096x2048 bf16 hi|lo
  float*          QQ   = (float*)(ws + 94371840);
  float*          KK   = (float*)(ws + 94633984);

  // one fused launch: x->AX, qkv_w->BW1, proj_w->BPW1 (BPW1 region free in
  // both phases: [83886080, 85983232) after QKVF's end, before QQ).
  split_all<<<8192, 256, 0, stream>>>(x, qkv_w, proj_w, AX, BW1, BPW1);

  // M=4096 N=3072 Kr=1024: 32x24 = 768 wgs (768%8==0 for XCD swizzle).
  // loN=2048: V-third tiles (n0>=2048) skip the lo product.
  gemm_bt2<0><<<768, 256, 0, stream>>>(AX, BW1, QKVF, nullptr, 24, 3072, 1024, 2048);

  prep<<<1024, 256, 0, stream>>>(QKVF, Q2, K2, V2, QQ, KK, curvature);

  // chunk=8 split-K: 5120 wave-tasks = 1280 WGs (the load balancer).
  attn_part<<<1280, 256, 0, stream>>>(Q2, K2, V2, QQ, KK, curvature, PART);

  attn_reduce<<<512, 256, 0, stream>>>(PART, AY);

  // M=4096 N=1024 Kr=1024: 32x8 = 256 wgs; loN=N_ -> never skip lo.
  gemm_bt2<1><<<256, 256, 0, stream>>>(AY, BPW1, out, proj_b, 8, 1024, 1024, 1024);
}